// Round 7
// baseline (53.461 us; speedup 1.0000x reference)
//
#include <hip/hip_runtime.h>

typedef __attribute__((ext_vector_type(8))) short bf16x8;
typedef __attribute__((ext_vector_type(4))) float f32x4;

#define B_    2048
#define S_    512

// ws layout (bytes)
#define OFF_WF1   0u          // Wfrag1[32 nt][4 ks][64 lane][8] bf16 = 131072
#define OFF_WF2   131072u     // Wfrag2[32][16][64][8] = 524288
#define OFF_WF3   655360u     // Wfrag3[32][16][64][8] = 524288
#define OFF_PREF  1179648u    // float pref[512][64] (50 used) = 131072
#define OFF_H1F   1310720u    // h1 frags [128 bt][16 ks][64][8] bf16 = 2097152
#define OFF_H2F   3407872u    // h2 frags, same = 2097152
#define OFF_EMBB  5505024u    // bf16 emb [50000][64] (one 128B line/row) = 6400000
#define WS_NEED   (OFF_EMBB + 6400000u)

__device__ __forceinline__ unsigned short f2bf(float f) {
    unsigned int u = __float_as_uint(f);
    u += 0x7FFFu + ((u >> 16) & 1u);          // round-to-nearest-even
    return (unsigned short)(u >> 16);
}

#define MFMA16(a, b, c) __builtin_amdgcn_mfma_f32_16x16x32_bf16((a), (b), (c), 0, 0, 0)

// ---------------- prep_convert: weights->fragment-order bf16, pos-prefix, emb
// Fragment word (ntile, ks, lane) elem j = W[k = ks*32 + (lane>>4)*8 + j][n = ntile*16 + (lane&15)]
__global__ __launch_bounds__(256) void prep_convert(
    const float* __restrict__ W1, const float* __restrict__ W2,
    const float* __restrict__ W3,
    const float* __restrict__ post, const int* __restrict__ pos,
    const float* __restrict__ emb,
    unsigned short* __restrict__ ws, float* __restrict__ pref, int do_emb)
{
    const int bid = blockIdx.x;
    const int tid = threadIdx.x;

    if (bid < 144) {                      // ---- weight convert, 64x64 (k,n) tile
        __shared__ float tile[64][65];
        const float* src; unsigned short* dst;
        int k0, n0, Ksrc, ksTot;
        if (bid < 64)       { src=W2; dst=ws+OFF_WF2/2; k0=(bid>>3)*64; n0=(bid&7)*64; Ksrc=512; ksTot=16; }
        else if (bid < 128) { int b=bid-64;  src=W3; dst=ws+OFF_WF3/2; k0=(b>>3)*64; n0=(b&7)*64; Ksrc=512; ksTot=16; }
        else                { int b=bid-128; src=W1; dst=ws+OFF_WF1/2; k0=(b>>3)*64; n0=(b&7)*64; Ksrc=100; ksTot=4;  }

        const int c  = tid & 63;
        const int r4 = tid >> 6;
#pragma unroll
        for (int rr = 0; rr < 16; ++rr) {
            int r = rr*4 + r4;
            float v = 0.f;
            if (k0 + r < Ksrc) v = src[(size_t)(k0+r)*512 + n0 + c];
            tile[r][c] = v;
        }
        __syncthreads();
        for (int w = tid; w < 8*64; w += 256) {
            int lane = w & 63, ks_l = (w >> 6) & 1, nt_l = w >> 7;
            int kr = ks_l*32 + ((lane >> 4) << 3);
            int nc = nt_l*16 + (lane & 15);
            uint4 wv;
            wv.x = (unsigned)f2bf(tile[kr+0][nc]) | ((unsigned)f2bf(tile[kr+1][nc]) << 16);
            wv.y = (unsigned)f2bf(tile[kr+2][nc]) | ((unsigned)f2bf(tile[kr+3][nc]) << 16);
            wv.z = (unsigned)f2bf(tile[kr+4][nc]) | ((unsigned)f2bf(tile[kr+5][nc]) << 16);
            wv.w = (unsigned)f2bf(tile[kr+6][nc]) | ((unsigned)f2bf(tile[kr+7][nc]) << 16);
            int ntile = (n0 >> 4) + nt_l, ks = (k0 >> 5) + ks_l;
            ((uint4*)dst)[(size_t)(ntile*ksTot + ks)*64 + lane] = wv;
        }
    } else if (bid == 144) {              // ---- pos-prefix (parallel, 4 chunks)
        __shared__ int   idx_s[512];
        __shared__ float csum[4][52];
        idx_s[tid]       = pos[tid];
        idx_s[tid + 256] = pos[tid + 256];
        __syncthreads();
        const int c = tid >> 6, d = tid & 63;
        if (d < 50) {
            float run = 0.f;
            for (int s = c*128; s < c*128 + 128; ++s)
                run += post[(size_t)idx_s[s]*50 + d];
            csum[c][d] = run;
        }
        __syncthreads();
        if (d < 50) {
            float run = 0.f;
            for (int cc = 0; cc < c; ++cc) run += csum[cc][d];
            for (int s = c*128; s < c*128 + 128; ++s) {
                run += post[(size_t)idx_s[s]*50 + d];
                pref[(size_t)s*64 + d] = run;
            }
        }
    } else {                              // ---- emb fp32 -> bf16, 64-padded rows
        if (!do_emb) return;
        unsigned short* embb = ws + OFF_EMBB/2;
        const int blk = bid - 145;
        const int r0  = blk * 128;
        if (r0 >= 50000) return;
        const int nr = min(128, 50000 - r0);
        for (int i = tid; i < nr * 64; i += 256) {
            int r = i >> 6, d = i & 63;
            float v = (d < 50) ? emb[(size_t)(r0 + r)*50 + d] : 0.f;
            embb[(size_t)(r0 + r)*64 + d] = f2bf(v);
        }
    }
}

// ---------------- pool_l1: pooling + layer 1, writes h1 fragments ------------
// 256 blocks x 512 thr; wave w pools row b0+w (8 lanes/token, 1 line/token),
// computes L1 (K=128) for cols w*64..+63, transposes D->A-frag via per-wave
// LDS, writes half-masked h1 frag words. Also inits out[b] = bf.
template<int EMODE>
__global__ __launch_bounds__(512, 2) void pool_l1(
    const float* __restrict__ emb, const int* __restrict__ seq,
    const int* __restrict__ seqlen, const unsigned short* __restrict__ ws_ro,
    unsigned short* __restrict__ ws_rw, const float* __restrict__ pref,
    const float* __restrict__ b1, const float* __restrict__ bfin,
    float* __restrict__ out)
{
    __shared__ __align__(16) unsigned short idx_s[8*512];     // 8 KB
    __shared__ __align__(16) unsigned short pooled_s[16*144]; // 4.6 KB
    __shared__ __align__(16) char tbuf[8*2304];               // 18.4 KB (16 rows x 144B/wave)

    const int tid  = threadIdx.x;
    const int wave = tid >> 6;
    const int lane = tid & 63;
    const int row  = lane & 15;
    const int kq   = lane >> 4;
    const int blk  = blockIdx.x;
    const int b0   = blk * 8;

    const unsigned short* WF1 = ws_ro + OFF_WF1 / 2;

    for (int i = tid; i < 8*512; i += 512)
        idx_s[i] = (unsigned short)seq[(size_t)b0 * S_ + i];
    for (int i = tid; i < 16*144; i += 512) pooled_s[i] = 0;
    if (tid < 16) out[b0*2 + tid] = bfin[tid & 1];

    // W1 fragments: coalesced, hide behind pooling
    bf16x8 w1f[4][4];
    {
        const bf16x8* bp1 = (const bf16x8*)WF1 + ((size_t)(wave*4) * 4 * 64) + lane;
#pragma unroll
        for (int ci = 0; ci < 4; ++ci)
#pragma unroll
            for (int ks = 0; ks < 4; ++ks) w1f[ci][ks] = bp1[(ci*4 + ks)*64];
    }
    __syncthreads();

    // ---- pooling
    const int L = seqlen[b0 + wave];
    const float Lf = (float)L;
    const unsigned short* idxr = idx_s + wave * 512;

    if (EMODE == 0) {
        const int tg = lane >> 3, dq = lane & 7;
        const uint4* tbl = (const uint4*)(ws_ro + OFF_EMBB / 2);
        float acc8[8];
#pragma unroll
        for (int j = 0; j < 8; ++j) acc8[j] = 0.f;

        const int Lfull = L & ~63;
        for (int s0 = 0; s0 < Lfull; s0 += 64) {
            uint4 q[8];
#pragma unroll
            for (int u = 0; u < 8; ++u) {
                int tok = idxr[s0 + u*8 + tg];
                q[u] = tbl[(size_t)tok * 8 + dq];
            }
#pragma unroll
            for (int u = 0; u < 8; ++u) {
                unsigned dw[4] = {q[u].x, q[u].y, q[u].z, q[u].w};
#pragma unroll
                for (int v = 0; v < 4; ++v) {
                    acc8[2*v]   += __uint_as_float(dw[v] << 16);
                    acc8[2*v+1] += __uint_as_float(dw[v] & 0xffff0000u);
                }
            }
        }
        for (int s0 = Lfull; s0 < L; s0 += 8) {
            int s = s0 + tg;
            uint4 q = {0u,0u,0u,0u};
            if (s < L) q = tbl[(size_t)idxr[s] * 8 + dq];
            unsigned dw[4] = {q.x, q.y, q.z, q.w};
#pragma unroll
            for (int v = 0; v < 4; ++v) {
                acc8[2*v]   += __uint_as_float(dw[v] << 16);
                acc8[2*v+1] += __uint_as_float(dw[v] & 0xffff0000u);
            }
        }
#pragma unroll
        for (int j = 0; j < 8; ++j) acc8[j] += __shfl_xor(acc8[j], 8);
#pragma unroll
        for (int j = 0; j < 8; ++j) acc8[j] += __shfl_xor(acc8[j], 16);
#pragma unroll
        for (int j = 0; j < 8; ++j) acc8[j] += __shfl_xor(acc8[j], 32);
        if (lane < 8) {
#pragma unroll
            for (int j = 0; j < 8; ++j) {
                int d = lane*8 + j;
                if (d < 50) pooled_s[wave*144 + d] = f2bf(acc8[j] / Lf);
            }
        }
    } else {
        float accE = 0.f;
        for (int s = 0; s < L; ++s) {
            int tok = idxr[s];
            if (lane < 50) accE += emb[(size_t)tok*50 + lane];
        }
        if (lane < 50) pooled_s[wave*144 + lane] = f2bf(accE / Lf);
    }
    if (lane < 50)
        pooled_s[wave*144 + 50 + lane] = f2bf(pref[(size_t)(L-1)*64 + lane] / Lf);
    __syncthreads();

    // ---- Layer 1 (K=128): rows 0..7 real (8..15 pad), cols wave*64..+63
    bf16x8 a1[4];
#pragma unroll
    for (int ks = 0; ks < 4; ++ks)
        a1[ks] = *(const bf16x8*)&pooled_s[row*144 + ks*32 + kq*8];

    char* tb = tbuf + wave*2304;
#pragma unroll
    for (int ci = 0; ci < 4; ++ci) {
        const float bb = b1[wave*64 + ci*16 + row];
        f32x4 acc = (f32x4){0.f,0.f,0.f,0.f};
#pragma unroll
        for (int ks = 0; ks < 4; ++ks) acc = MFMA16(a1[ks], w1f[ci][ks], acc);
#pragma unroll
        for (int r = 0; r < 4; ++r)
            *(unsigned short*)(tb + (kq*4 + r)*144 + (ci*16 + row)*2) =
                f2bf(fmaxf(acc[r] + bb, 0.f));
    }

    // read A-frag-order words (rows 0..7 local), masked global write
    unsigned short* h1f = ws_rw + OFF_H1F/2;
    const int bt = blk >> 1;
    const bool mine = ((row >> 3) == (blk & 1));
    const int lr = row & 7;
#pragma unroll
    for (int ksl = 0; ksl < 2; ++ksl) {
        bf16x8 wv = *(const bf16x8*)(tb + lr*144 + ksl*64 + kq*16);
        if (mine)
            ((bf16x8*)h1f)[(size_t)(bt*16 + wave*2 + ksl)*64 + lane] = wv;
    }
}

// ---------------- layer_kernel<L>: one 512x512 dense layer, 2D-tiled ---------
// grid 256 = 32 Mtiles(64 rows) x 8 Ntiles(64 cols); 8 waves = 4 mw x 2 nw.
// B slice (4 ntiles, 64KB, fragment-order = linear) staged via global_load_lds.
// L==2: write h2 frags (per-wave LDS D->A transpose). L==3: fused final
// projection: relu tile . Wf (fp32) -> shfl reduce -> atomicAdd into out.
template<int LAYER>
__global__ __launch_bounds__(512, 2) void layer_kernel(
    const unsigned short* __restrict__ ws_ro, unsigned short* __restrict__ ws_rw,
    const float* __restrict__ bias, const float* __restrict__ Wf,
    float* __restrict__ out)
{
    __shared__ __align__(16) char Bst[65536];
    __shared__ __align__(16) char tbuf[8*1536];   // 16 rows x 96B per wave

    const int tid  = threadIdx.x;
    const int wave = tid >> 6;
    const int lane = tid & 63;
    const int row  = lane & 15;
    const int kq   = lane >> 4;
    const int mb   = blockIdx.x >> 3;
    const int nb   = blockIdx.x & 7;
    const int mw   = wave >> 1;
    const int nw   = wave & 1;
    const int bt   = mb*4 + mw;

    const unsigned short* WF = ws_ro + (LAYER==2 ? OFF_WF2 : OFF_WF3)/2;
    const bf16x8* hin = (const bf16x8*)(ws_ro + (LAYER==2 ? OFF_H1F : OFF_H2F)/2);

    // stage B slice (ntiles nb*4..+3 = 64KB) linearly into LDS
    {
        const char* src = (const char*)WF + (size_t)(nb*4) * 16 * 1024;
#pragma unroll
        for (int it = 0; it < 8; ++it)
            __builtin_amdgcn_global_load_lds(
                (const __attribute__((address_space(1))) unsigned int*)(src + it*8192 + tid*16),
                (__attribute__((address_space(3))) unsigned int*)(Bst + it*8192 + tid*16),
                16, 0, 0);
    }

    // A fragments (issued pre-barrier; barrier drains vmcnt)
    bf16x8 a[16];
#pragma unroll
    for (int ks = 0; ks < 16; ++ks)
        a[ks] = hin[(size_t)(bt*16 + ks)*64 + lane];
    __syncthreads();

    f32x4 acc0 = (f32x4){0.f,0.f,0.f,0.f};
    f32x4 acc1 = (f32x4){0.f,0.f,0.f,0.f};
    const char* bp0 = Bst + (size_t)(nw*2 + 0)*16*1024 + lane*16;
    const char* bp1 = Bst + (size_t)(nw*2 + 1)*16*1024 + lane*16;
#pragma unroll
    for (int ks = 0; ks < 16; ++ks) {
        bf16x8 bv0 = *(const bf16x8*)(bp0 + ks*1024);
        bf16x8 bv1 = *(const bf16x8*)(bp1 + ks*1024);
        acc0 = MFMA16(a[ks], bv0, acc0);
        acc1 = MFMA16(a[ks], bv1, acc1);
    }

    const int nt0 = nb*4 + nw*2, nt1 = nt0 + 1;
    const float bb0 = bias[nt0*16 + row], bb1 = bias[nt1*16 + row];

    if (LAYER == 2) {
        char* tb = tbuf + wave*1536;
#pragma unroll
        for (int r = 0; r < 4; ++r) {
            *(unsigned short*)(tb + (kq*4 + r)*96 + row*2) =
                f2bf(fmaxf(acc0[r] + bb0, 0.f));
            *(unsigned short*)(tb + (kq*4 + r)*96 + (16 + row)*2) =
                f2bf(fmaxf(acc1[r] + bb1, 0.f));
        }
        bf16x8 wv = *(const bf16x8*)(tb + row*96 + kq*16);
        unsigned short* h2f = ws_rw + OFF_H2F/2;
        ((bf16x8*)h2f)[(size_t)(bt*16 + nb*2 + nw)*64 + lane] = wv;
    } else {
        float v0[4], v1[4];
#pragma unroll
        for (int r = 0; r < 4; ++r) {
            v0[r] = fmaxf(acc0[r] + bb0, 0.f);
            v1[r] = fmaxf(acc1[r] + bb1, 0.f);
        }
        const float2 wf0 = ((const float2*)Wf)[nt0*16 + row];
        const float2 wf1 = ((const float2*)Wf)[nt1*16 + row];
        float po[4][2];
#pragma unroll
        for (int r = 0; r < 4; ++r) {
            po[r][0] = v0[r]*wf0.x + v1[r]*wf1.x;
            po[r][1] = v0[r]*wf0.y + v1[r]*wf1.y;
        }
#pragma unroll
        for (int s = 1; s < 16; s <<= 1)
#pragma unroll
            for (int r = 0; r < 4; ++r) {
                po[r][0] += __shfl_xor(po[r][0], s);
                po[r][1] += __shfl_xor(po[r][1], s);
            }
        if (row == 0) {
#pragma unroll
            for (int r = 0; r < 4; ++r) {
                atomicAdd(&out[(size_t)(bt*16 + kq*4 + r)*2 + 0], po[r][0]);
                atomicAdd(&out[(size_t)(bt*16 + kq*4 + r)*2 + 1], po[r][1]);
            }
        }
    }
}

extern "C" void kernel_launch(void* const* d_in, const int* in_sizes, int n_in,
                              void* d_out, int out_size, void* d_ws, size_t ws_size,
                              hipStream_t stream)
{
    const float* emb    = (const float*)d_in[0];
    const float* post   = (const float*)d_in[1];
    const float* W1     = (const float*)d_in[2];
    const float* b1     = (const float*)d_in[3];
    const float* W2     = (const float*)d_in[4];
    const float* b2     = (const float*)d_in[5];
    const float* W3     = (const float*)d_in[6];
    const float* b3     = (const float*)d_in[7];
    const float* Wf     = (const float*)d_in[8];
    const float* bf     = (const float*)d_in[9];
    const int*   seq    = (const int*)d_in[10];
    const int*   seqlen = (const int*)d_in[11];
    const int*   pos    = (const int*)d_in[12];
    float*       out    = (float*)d_out;

    unsigned short* ws = (unsigned short*)d_ws;
    float* pref = (float*)((char*)d_ws + OFF_PREF);
    const int do_emb = (ws_size >= (size_t)WS_NEED) ? 1 : 0;

    prep_convert<<<536, 256, 0, stream>>>(W1, W2, W3, post, pos, emb,
                                          ws, pref, do_emb);
    if (do_emb)
        pool_l1<0><<<256, 512, 0, stream>>>(emb, seq, seqlen, ws, ws, pref,
                                            b1, bf, out);
    else
        pool_l1<1><<<256, 512, 0, stream>>>(emb, seq, seqlen, ws, ws, pref,
                                            b1, bf, out);
    layer_kernel<2><<<256, 512, 0, stream>>>(ws, ws, b2, Wf, out);
    layer_kernel<3><<<256, 512, 0, stream>>>(ws, ws, b3, Wf, out);
}